// Round 18
// baseline (440.032 us; speedup 1.0000x reference)
//
#include <hip/hip_runtime.h>
#include <hip/hip_bf16.h>

// MSA Transformer block: B=1, S=64, L=256, DM=256, DP=128, H=8, HT=4, NO=32
// Round 18: attn Q-chunk split across blockIdx.z (row 512->1024, tri 1024->2048
// blocks); OPM U-slot xor-shift swizzle pi(g)=g^(g>>3) on write AND read.

#define S_ 64
#define L_ 256
#define DM_ 256
#define DP_ 128
#define H_ 8
#define HT_ 4
#define NO_ 32

typedef __hip_bfloat16 bf16;
typedef short short4s __attribute__((ext_vector_type(4)));
typedef short short8 __attribute__((ext_vector_type(8)));
typedef float floatx4 __attribute__((ext_vector_type(4)));

__device__ __forceinline__ short f2bfs(float x) {
  union { float f; unsigned u; } v;
  v.f = x;
  unsigned r = (v.u + 0x7fffu + ((v.u >> 16) & 1u)) >> 16;
  return (short)r;
}

// ---------------- layernorm (4 rows per 256-thr block, 1 wave per row) ----------------
__global__ void k_ln(const float* __restrict__ src, bf16* __restrict__ dst,
                     const float* __restrict__ g, const float* __restrict__ bta, int D) {
  int row = blockIdx.x * 4 + (threadIdx.x >> 6);
  const float* x = src + (size_t)row * D;
  bf16* y = dst + (size_t)row * D;
  int t = threadIdx.x & 63;
  float v[4];
  int cnt = 0;
  float sum = 0.f;
  for (int e = t; e < D; e += 64) { float xv = x[e]; v[cnt++] = xv; sum += xv; }
  #pragma unroll
  for (int o = 32; o; o >>= 1) sum += __shfl_down(sum, o);
  sum = __shfl(sum, 0);
  float mean = sum / D;
  float var = 0.f;
  for (int k = 0; k < cnt; k++) { float d = v[k] - mean; var += d * d; }
  #pragma unroll
  for (int o = 32; o; o >>= 1) var += __shfl_down(var, o);
  var = __shfl(var, 0);
  float rstd = rsqrtf(var / D + 1e-5f);
  cnt = 0;
  for (int e = t; e < D; e += 64)
    y[e] = __float2bfloat16((v[cnt++] - mean) * rstd * g[e] + bta[e]);
}

// ---------------- fused weight transpose: 10 jobs, one launch ----------------
struct WtJob { const float* W; bf16* Wt; int K; int N; int nblk; };
struct WtJobs { WtJob j[10]; };

__global__ void k_wt_all(WtJobs jobs) {
  __shared__ float tile[32][33];
  int b = blockIdx.x;
  int ji = 0;
  while (ji < 9 && b >= jobs.j[ji].nblk) { b -= jobs.j[ji].nblk; ji++; }
  const float* W = jobs.j[ji].W;
  bf16* Wt = jobs.j[ji].Wt;
  int K = jobs.j[ji].K, N = jobs.j[ji].N;
  int kt = K >> 5;
  int k0 = (b % kt) * 32, n0 = (b / kt) * 32;
  int tid = threadIdx.x; // 256
  for (int e = tid; e < 1024; e += 256) {
    int r = e >> 5, c = e & 31;
    tile[r][c] = W[(size_t)(k0 + r) * N + (n0 + c)];
  }
  __syncthreads();
  for (int e = tid; e < 1024; e += 256) {
    int r = e >> 5, c = e & 31;
    Wt[(size_t)(n0 + r) * K + (k0 + c)] = __float2bfloat16(tile[c][r]);
  }
}

// ---------------- OPM proj weight permute + ab-bias concat ----------------
__global__ void k_wtopm(const float* __restrict__ W, bf16* __restrict__ Wt,
                        const float* __restrict__ ba, const float* __restrict__ bb,
                        float* __restrict__ bias_ab) {
  if (blockIdx.x == 0 && threadIdx.x < 64)
    bias_ab[threadIdx.x] = threadIdx.x < 32 ? ba[threadIdx.x] : bb[threadIdx.x - 32];
  int idx = blockIdx.x * 256 + threadIdx.x; // 131072
  int d = idx >> 10, kk = idx & 1023;
  int e = kk >> 5, c = kk & 31;
  Wt[idx] = __float2bfloat16(W[(size_t)(c * 32 + e) * 128 + d]);
}

// ---------------- bf16 MFMA GEMM, 64x64 tile, optional fused LayerNorm ----------------
// MODE: 0 Cf=v | 1 Cf+=v | 2 Cb=bf16(v) | 3 Cb=bf16(relu v) | 4 Cf=Csrc+v
//       5 t=Cf+v; Cf=t; Cdup=t | 6 opm-ab: write transposed to a_t(Cb)/b_t(Cdup)
template<int MODE, int LNF>
__global__ void k_gemm64(const bf16* __restrict__ A, const bf16* __restrict__ Wt,
                         const float* __restrict__ bias, float* __restrict__ Cf,
                         bf16* __restrict__ Cb, const float* __restrict__ Csrc,
                         float* __restrict__ Cdup, int M, int N, int K, float scale,
                         const float* __restrict__ Af = nullptr,
                         const float* __restrict__ lng = nullptr,
                         const float* __restrict__ lnbt = nullptr) {
  __shared__ short As[64 * 64];
  __shared__ short Bs[64 * 64];
  __shared__ float sMean[64];
  __shared__ float sRstd[64];
  const int tid = threadIdx.x;
  const int nwg = gridDim.x * gridDim.y;
  const int wgid = blockIdx.y * gridDim.x + blockIdx.x;
  const int q = nwg >> 3, r8 = nwg & 7;
  const int xcd = wgid & 7, loc = wgid >> 3;
  const int swz = (xcd < r8 ? xcd * (q + 1) : r8 * (q + 1) + (xcd - r8) * q) + loc;
  const int by = swz / gridDim.x, bx = swz - by * gridDim.x;
  const int m0 = by * 64, n0 = bx * 64;
  const int w = tid >> 6, l = tid & 63;
  const int wm = (w >> 1) * 32, wn = (w & 1) * 32;
  const int lr = l & 15, lk = l >> 4;

  if (LNF) {
    int rr = tid >> 2, quad = tid & 3;
    const float* xr = Af + (size_t)(m0 + rr) * 256 + quad * 64;
    float s = 0.f, s2 = 0.f;
    #pragma unroll
    for (int ii = 0; ii < 16; ii++) {
      floatx4 x = *(const floatx4*)(xr + ii * 4);
      #pragma unroll
      for (int jj = 0; jj < 4; jj++) { s += x[jj]; s2 += x[jj] * x[jj]; }
    }
    #pragma unroll
    for (int o = 1; o <= 2; o <<= 1) { s += __shfl_xor(s, o); s2 += __shfl_xor(s2, o); }
    if (quad == 0) {
      float mean = s * 0.00390625f;
      float var = s2 * 0.00390625f - mean * mean;
      sMean[rr] = mean;
      sRstd[rr] = rsqrtf(var + 1e-5f);
    }
    __syncthreads();
  }

  floatx4 acc[2][2] = {};
  const short* Ash = (const short*)A;
  const short* Bsh = (const short*)Wt;
  for (int k0 = 0; k0 < K; k0 += 64) {
    if (LNF) {
      for (int e = tid; e < 512; e += 256) {
        int r = e >> 3, kg = e & 7;
        int kb = k0 + kg * 8;
        const float* src = Af + (size_t)(m0 + r) * 256 + kb;
        floatx4 x0 = *(const floatx4*)(src);
        floatx4 x1 = *(const floatx4*)(src + 4);
        float mean = sMean[r], rstd = sRstd[r];
        short8 v;
        #pragma unroll
        for (int jj = 0; jj < 4; jj++) {
          v[jj] = f2bfs((x0[jj] - mean) * rstd * lng[kb + jj] + lnbt[kb + jj]);
          v[jj + 4] = f2bfs((x1[jj] - mean) * rstd * lng[kb + 4 + jj] + lnbt[kb + 4 + jj]);
        }
        *(short8*)(&As[r * 64 + ((kg ^ (r & 7)) * 8)]) = v;
      }
    } else {
      for (int e = tid; e < 512; e += 256) {
        int r = e >> 3, kg = e & 7;
        short8 v = *(const short8*)(Ash + (size_t)(m0 + r) * K + k0 + kg * 8);
        *(short8*)(&As[r * 64 + ((kg ^ (r & 7)) * 8)]) = v;
      }
    }
    for (int e = tid; e < 512; e += 256) {
      int r = e >> 3, kg = e & 7;
      int n = n0 + r;
      short8 v = {0, 0, 0, 0, 0, 0, 0, 0};
      if (n < N) v = *(const short8*)(Bsh + (size_t)n * K + k0 + kg * 8);
      *(short8*)(&Bs[r * 64 + ((kg ^ (r & 7)) * 8)]) = v;
    }
    __syncthreads();
    #pragma unroll
    for (int kk = 0; kk < 2; kk++) {
      short8 af[2], bfr[2];
      #pragma unroll
      for (int mi = 0; mi < 2; mi++) {
        int row = wm + mi * 16 + lr;
        int kg = kk * 4 + lk;
        af[mi] = *(const short8*)(&As[row * 64 + ((kg ^ (row & 7)) * 8)]);
      }
      #pragma unroll
      for (int ni = 0; ni < 2; ni++) {
        int row = wn + ni * 16 + lr;
        int kg = kk * 4 + lk;
        bfr[ni] = *(const short8*)(&Bs[row * 64 + ((kg ^ (row & 7)) * 8)]);
      }
      #pragma unroll
      for (int mi = 0; mi < 2; mi++)
        #pragma unroll
        for (int ni = 0; ni < 2; ni++)
          acc[mi][ni] = __builtin_amdgcn_mfma_f32_16x16x32_bf16(af[mi], bfr[ni], acc[mi][ni], 0, 0, 0);
    }
    __syncthreads();
  }
  #pragma unroll
  for (int ni = 0; ni < 2; ni++) {
    int n = n0 + wn + ni * 16 + lr;
    if (n >= N) continue;
    float bv = bias ? bias[n] : 0.f;
    #pragma unroll
    for (int mi = 0; mi < 2; mi++) {
      int mbase = m0 + wm + mi * 16 + lk * 4;
      #pragma unroll
      for (int r = 0; r < 4; r++) {
        float v = acc[mi][ni][r] * scale + bv;
        size_t idx = (size_t)(mbase + r) * N + n;
        if (MODE == 0) Cf[idx] = v;
        else if (MODE == 1) Cf[idx] += v;
        else if (MODE == 2) Cb[idx] = __float2bfloat16(v);
        else if (MODE == 3) Cb[idx] = __float2bfloat16(fmaxf(v, 0.f));
        else if (MODE == 4) Cf[idx] = Csrc[idx] + v;
        else if (MODE == 5) { float t = Cf[idx] + v; Cf[idx] = t; Cdup[idx] = t; }
        else if (MODE == 6) {
          int m = mbase + r;
          int s = m >> 8, i2 = m & 255;
          int y = n >> 5, c = n & 31;
          bf16* outp = y ? (bf16*)Cdup : Cb;
          outp[((size_t)i2 * NO_ + c) * S_ + s] = __float2bfloat16(v);
        }
      }
    }
  }
}

// ---------------- fused OPM, 512 threads; U-slot xor-shift swizzle pi(g)=g^(g>>3) ----------------
__global__ __launch_bounds__(512) void k_opm_fused(
    const bf16* __restrict__ a_t, const bf16* __restrict__ b_t,
    const bf16* __restrict__ Wt, const float* __restrict__ bias,
    const float* __restrict__ pair_in, float* __restrict__ pair_out) {
  __shared__ short U[32 * 512]; // 32 KB
  const int i = blockIdx.y;
  const int jg = blockIdx.x; // 0..7
  const int tid = threadIdx.x;
  const int w = tid >> 6, l = tid & 63;   // w in 0..7
  const int lr = l & 15, lk = l >> 4;
  const short* at = (const short*)a_t;
  const short* bt = (const short*)b_t;
  const short* wt = (const short*)Wt;

  short8 af[2][2];
  #pragma unroll
  for (int kh = 0; kh < 2; kh++)
    #pragma unroll
    for (int ks = 0; ks < 2; ks++)
      af[kh][ks] = *(const short8*)(at + ((size_t)i * 32 + kh * 16 + lr) * 64 + ks * 32 + lk * 8);

  floatx4 pacc[2] = {};
  #pragma unroll
  for (int kh = 0; kh < 2; kh++) {
    #pragma unroll
    for (int sc = 0; sc < 2; sc++) {
      floatx4 uacc[4] = {};
      const size_t rowbase = ((size_t)(jg * 32 + sc * 16) << 5) + w * 64;
      #pragma unroll
      for (int ks = 0; ks < 2; ks++)
        #pragma unroll
        for (int nt = 0; nt < 4; nt++) {
          short8 bfr = *(const short8*)(bt + (rowbase + nt * 16 + lr) * 64 + ks * 32 + lk * 8);
          uacc[nt] = __builtin_amdgcn_mfma_f32_16x16x32_bf16(af[kh][ks], bfr, uacc[nt], 0, 0, 0);
        }
      #pragma unroll
      for (int nt = 0; nt < 4; nt++) {
        int npos = w * 64 + nt * 16 + lr;
        int jj = sc * 16 + (npos >> 5);
        int e = npos & 31;
        int g = e * 2 + (lk >> 1);
        int sg = (g ^ (g >> 3)) ^ (jj & 7);   // xor-shift slot swizzle
        int off = (lk & 1) * 4;
        short4s pk;
        pk.x = f2bfs(uacc[nt][0] * 0.015625f);
        pk.y = f2bfs(uacc[nt][1] * 0.015625f);
        pk.z = f2bfs(uacc[nt][2] * 0.015625f);
        pk.w = f2bfs(uacc[nt][3] * 0.015625f);
        *(short4s*)(&U[jj * 512 + (sg << 3) + off]) = pk;
      }
    }
    __syncthreads();
    #pragma unroll 4
    for (int ks = 0; ks < 16; ks++) {
      short8 afp[2];
      #pragma unroll
      for (int mt = 0; mt < 2; mt++) {
        int row = mt * 16 + lr;
        int g = ks * 4 + lk;
        int sg = (g ^ (g >> 3)) ^ (row & 7);  // same pi on read
        afp[mt] = *(const short8*)(&U[row * 512 + (sg << 3)]);
      }
      int wko = (ks * 2 + (lk >> 1)) * 32 + kh * 16 + (lk & 1) * 8;
      int d = w * 16 + lr;
      short8 bfr = *(const short8*)(wt + (size_t)d * 1024 + wko);
      #pragma unroll
      for (int mt = 0; mt < 2; mt++)
        pacc[mt] = __builtin_amdgcn_mfma_f32_16x16x32_bf16(afp[mt], bfr, pacc[mt], 0, 0, 0);
    }
    __syncthreads();
  }
  int jbase = jg * 32;
  int d = w * 16 + lr;
  float bv = bias[d];
  #pragma unroll
  for (int mt = 0; mt < 2; mt++)
    #pragma unroll
    for (int r = 0; r < 4; r++) {
      int j = jbase + mt * 16 + lk * 4 + r;
      size_t idx = ((size_t)i * L_ + j) * DP_ + d;
      pair_out[idx] = pair_in[idx] + pacc[mt][r] + bv;
    }
}

// ---------------- MFMA attention: (lead, head, zchunk); K/V staged per block ----------------
template<int N, int ZSP>
__global__ __launch_bounds__(256) void k_attn_mfma(
    const bf16* __restrict__ qkv, bf16* __restrict__ out, int dmodel,
    int tokStride, int leadStride, int otokStride, int oleadStride, float scale) {
  constexpr int NT = N / 16;
  constexpr int NK = N / 32;
  constexpr int NIC = N / 64;
  constexpr int NICB = NIC / ZSP;   // chunks per block
  __shared__ short Ks[N * 32];
  __shared__ short Vt[N * 32];
  __shared__ short Qs[2048];
  __shared__ short P[64 * N];

  const int lead = blockIdx.x;
  const int h = blockIdx.y;
  const int ic0 = blockIdx.z * NICB;
  const short* base = (const short*)qkv + (size_t)lead * leadStride;
  const int qoff = h * 32, koff = dmodel + h * 32, voff = 2 * dmodel + h * 32;
  const int tid = threadIdx.x;
  const int l = tid & 63, w = tid >> 6;
  const int lr = l & 15, lk = l >> 4;

  for (int e = tid; e < N * 4; e += 256) {
    int j = e >> 2, kg = e & 3;
    short8 v = *(const short8*)(base + (size_t)j * tokStride + koff + kg * 8);
    *(short8*)(&Ks[(kg * N + j) * 8]) = v;
  }
  for (int e = tid; e < N * 32; e += 256) {
    int j = e >> 5, d = e & 31;
    Vt[((j >> 5) * 4 + ((j >> 3) & 3)) * 256 + d * 8 + (j & 7)] = base[(size_t)j * tokStride + voff + d];
  }
  __syncthreads();

  for (int ic = ic0; ic < ic0 + NICB; ic++) {
    {
      int r = tid >> 2, kg = tid & 3;
      short8 v = *(const short8*)(base + (size_t)(ic * 64 + r) * tokStride + qoff + kg * 8);
      *(short8*)(&Qs[(kg * 64 + r) * 8]) = v;
    }
    short8 aq = *(const short8*)(&Qs[(lk * 64 + w * 16 + lr) * 8]);
    floatx4 sa[NT];
    #pragma unroll
    for (int t = 0; t < NT; t++) {
      short8 bk = *(const short8*)(&Ks[(lk * N + t * 16 + lr) * 8]);
      floatx4 z = {0.f, 0.f, 0.f, 0.f};
      sa[t] = __builtin_amdgcn_mfma_f32_16x16x32_bf16(aq, bk, z, 0, 0, 0);
    }

    float mrow[4] = {-1e30f, -1e30f, -1e30f, -1e30f};
    #pragma unroll
    for (int t = 0; t < NT; t++)
      #pragma unroll
      for (int r = 0; r < 4; r++) {
        float s = fminf(fmaxf(sa[t][r] * scale, -50.f), 50.f);
        sa[t][r] = s;
        mrow[r] = fmaxf(mrow[r], s);
      }
    #pragma unroll
    for (int o = 1; o <= 8; o <<= 1)
      #pragma unroll
      for (int r = 0; r < 4; r++) mrow[r] = fmaxf(mrow[r], __shfl_xor(mrow[r], o));
    float srow[4] = {0.f, 0.f, 0.f, 0.f};
    #pragma unroll
    for (int t = 0; t < NT; t++)
      #pragma unroll
      for (int r = 0; r < 4; r++) {
        float p = __expf(sa[t][r] - mrow[r]);
        sa[t][r] = p;
        srow[r] += p;
      }
    #pragma unroll
    for (int o = 1; o <= 8; o <<= 1)
      #pragma unroll
      for (int r = 0; r < 4; r++) srow[r] += __shfl_xor(srow[r], o);
    float inv[4];
    #pragma unroll
    for (int r = 0; r < 4; r++) inv[r] = 1.f / srow[r];

    #pragma unroll
    for (int t = 0; t < NT; t++) {
      int c = t * 16 + lr;
      int kstep = c >> 5, kslot = (c >> 3) & 3, u = c & 7;
      #pragma unroll
      for (int r = 0; r < 4; r++) {
        int row = w * 16 + lk * 4 + r;
        P[((kstep * 4 + kslot) * 64 + row) * 8 + u] = f2bfs(sa[t][r] * inv[r]);
      }
    }

    floatx4 oacc[2] = {{0.f,0.f,0.f,0.f},{0.f,0.f,0.f,0.f}};
    #pragma unroll
    for (int ks = 0; ks < NK; ks++) {
      short8 ap = *(const short8*)(&P[((ks * 4 + lk) * 64 + w * 16 + lr) * 8]);
      #pragma unroll
      for (int ct = 0; ct < 2; ct++) {
        short8 bv = *(const short8*)(&Vt[((ks * 4 + lk) * 32 + ct * 16 + lr) * 8]);
        oacc[ct] = __builtin_amdgcn_mfma_f32_16x16x32_bf16(ap, bv, oacc[ct], 0, 0, 0);
      }
    }
    bf16* ob = out + (size_t)lead * oleadStride + h * 32;
    #pragma unroll
    for (int ct = 0; ct < 2; ct++)
      #pragma unroll
      for (int r = 0; r < 4; r++) {
        int tok = ic * 64 + w * 16 + lk * 4 + r;
        ob[(size_t)tok * otokStride + ct * 16 + lr] = __float2bfloat16(oacc[ct][r]);
      }
  }
}

extern "C" void kernel_launch(void* const* d_in, const int* in_sizes, int n_in,
                              void* d_out, int out_size, void* d_ws, size_t ws_size,
                              hipStream_t stream) {
  const float* msa_in    = (const float*)d_in[0];
  const float* pair_in   = (const float*)d_in[1];
  const float* row_ng    = (const float*)d_in[2];
  const float* row_nb    = (const float*)d_in[3];
  const float* row_qkv_w = (const float*)d_in[4];
  const float* row_qkv_b = (const float*)d_in[5];
  const float* row_out_w = (const float*)d_in[6];
  const float* row_out_b = (const float*)d_in[7];
  const float* col_ng    = (const float*)d_in[8];
  const float* col_nb    = (const float*)d_in[9];
  const float* col_qkv_w = (const float*)d_in[10];
  const float* col_qkv_b = (const float*)d_in[11];
  const float* col_out_w = (const float*)d_in[12];
  const float* col_out_b = (const float*)d_in[13];
  const float* ff_ng     = (const float*)d_in[14];
  const float* ff_nb     = (const float*)d_in[15];
  const float* ff_w1     = (const float*)d_in[16];
  const float* ff_b1     = (const float*)d_in[17];
  const float* ff_w2     = (const float*)d_in[18];
  const float* ff_b2     = (const float*)d_in[19];
  const float* op_ng     = (const float*)d_in[20];
  const float* op_nb     = (const float*)d_in[21];
  const float* op_a_w    = (const float*)d_in[22];
  const float* op_a_b    = (const float*)d_in[23];
  const float* op_b_w    = (const float*)d_in[24];
  const float* op_b_b    = (const float*)d_in[25];
  const float* op_out_w  = (const float*)d_in[26];
  const float* op_out_b  = (const float*)d_in[27];
  const float* tri_ng    = (const float*)d_in[28];
  const float* tri_nb    = (const float*)d_in[29];
  const float* tri_qkv_w = (const float*)d_in[30];
  const float* tri_qkv_b = (const float*)d_in[31];
  const float* tri_out_w = (const float*)d_in[32];
  const float* tri_out_b = (const float*)d_in[33];

  const int MT = S_ * L_;   // 16384
  const int PT = L_ * L_;   // 65536

  // ---- arena (byte offsets) ----
  char* ws = (char*)d_ws;
  float* msa_f  = (float*)(ws);                    // 16 MB
  float* pair_f = (float*)(ws + 16777216);         // 32 MB
  char*  X      = ws + 50331648;                   // 48 MB scratch (qkv bf16 / ffh bf16)
  bf16*  ln_b   = (bf16*)(ws + 100663296);         // 16 MB
  bf16*  ao_b   = (bf16*)(ws + 117440512);         // 16 MB
  bf16*  a_t    = (bf16*)(ws + 136314880);         // 1 MB
  bf16*  b_t    = (bf16*)(ws + 137363456);         // 1 MB
  bf16*  wts    = (bf16*)(ws + 138412032);         // ~2.6 MB
  float* bias_ab = (float*)(ws + 141557760);       // 64 floats

  bf16* row_qkv_wt = wts;                 // 768*256
  bf16* col_qkv_wt = row_qkv_wt + 196608;
  bf16* row_out_wt = col_qkv_wt + 196608; // 256*256
  bf16* col_out_wt = row_out_wt + 65536;
  bf16* ff_w1t     = col_out_wt + 65536;  // 1024*256
  bf16* ff_w2t     = ff_w1t + 262144;     // 256*1024
  bf16* op_ab_wt   = ff_w2t + 262144;     // 64*256
  bf16* op_out_wt  = op_ab_wt + 16384;    // 128*1024 (ec-permuted)
  bf16* tri_qkv_wt = op_out_wt + 131072;  // 384*128
  bf16* tri_out_wt = tri_qkv_wt + 49152;  // 128*128

  bf16* qkv_bf = (bf16*)X;
  bf16* ffh    = (bf16*)X;

  float* dout_msa  = (float*)d_out;
  float* dout_pair = (float*)d_out + (size_t)MT * DM_;

  const float scale = 0.17677669529663687f; // 1/sqrt(32)

  // ---- weight prep: 2 launches total ----
  WtJobs jobs;
  jobs.j[0] = {row_qkv_w, row_qkv_wt, 256, 768, 192};
  jobs.j[1] = {col_qkv_w, col_qkv_wt, 256, 768, 192};
  jobs.j[2] = {row_out_w, row_out_wt, 256, 256, 64};
  jobs.j[3] = {col_out_w, col_out_wt, 256, 256, 64};
  jobs.j[4] = {ff_w1, ff_w1t, 256, 1024, 256};
  jobs.j[5] = {ff_w2, ff_w2t, 1024, 256, 256};
  jobs.j[6] = {op_a_w, op_ab_wt, 256, 32, 8};
  jobs.j[7] = {op_b_w, op_ab_wt + 32 * 256, 256, 32, 8};
  jobs.j[8] = {tri_qkv_w, tri_qkv_wt, 128, 384, 48};
  jobs.j[9] = {tri_out_w, tri_out_wt, 128, 128, 16};
  k_wt_all<<<1104, 256, 0, stream>>>(jobs);
  k_wtopm<<<512, 256, 0, stream>>>(op_out_w, op_out_wt, op_a_b, op_b_b, bias_ab);

  // ---- 1. row attention (attend over L) ----
  k_ln<<<MT / 4, 256, 0, stream>>>(msa_in, ln_b, row_ng, row_nb, DM_);
  k_gemm64<2,0><<<dim3(12, 256), 256, 0, stream>>>(ln_b, row_qkv_wt, row_qkv_b, nullptr, qkv_bf, nullptr, nullptr, MT, 768, 256, 1.f);
  k_attn_mfma<256,2><<<dim3(S_, H_, 2), 256, 0, stream>>>(qkv_bf, ao_b, DM_, 768, L_ * 768, DM_, L_ * DM_, scale);
  k_gemm64<4,0><<<dim3(4, 256), 256, 0, stream>>>(ao_b, row_out_wt, row_out_b, msa_f, nullptr, msa_in, nullptr, MT, DM_, DM_, 1.f);

  // ---- 2. column attention (attend over S) ----
  k_ln<<<MT / 4, 256, 0, stream>>>(msa_f, ln_b, col_ng, col_nb, DM_);
  k_gemm64<2,0><<<dim3(12, 256), 256, 0, stream>>>(ln_b, col_qkv_wt, col_qkv_b, nullptr, qkv_bf, nullptr, nullptr, MT, 768, 256, 1.f);
  k_attn_mfma<64,1><<<dim3(L_, H_, 1), 256, 0, stream>>>(qkv_bf, ao_b, DM_, L_ * 768, 768, L_ * DM_, DM_, scale);
  k_gemm64<1,0><<<dim3(4, 256), 256, 0, stream>>>(ao_b, col_out_wt, col_out_b, msa_f, nullptr, nullptr, nullptr, MT, DM_, DM_, 1.f);

  // ---- 3. feed-forward (down-proj also writes d_out msa) ----
  k_ln<<<MT / 4, 256, 0, stream>>>(msa_f, ln_b, ff_ng, ff_nb, DM_);
  k_gemm64<3,0><<<dim3(16, 256), 256, 0, stream>>>(ln_b, ff_w1t, ff_b1, nullptr, ffh, nullptr, nullptr, MT, 1024, 256, 1.f);
  k_gemm64<5,0><<<dim3(4, 256), 256, 0, stream>>>(ffh, ff_w2t, ff_b2, msa_f, nullptr, nullptr, dout_msa, MT, DM_, 1024, 1.f);

  // ---- 4. outer product mean -> pair (LN fused; transposed write; grid.x==1) ----
  k_gemm64<6,1><<<dim3(1, 256), 256, 0, stream>>>(nullptr, op_ab_wt, bias_ab, nullptr, a_t, nullptr, (float*)b_t, MT, 64, 256, 1.f, msa_f, op_ng, op_nb);
  k_opm_fused<<<dim3(8, L_), 512, 0, stream>>>(a_t, b_t, op_out_wt, op_out_b, pair_in, pair_f);

  // ---- 5. triangle attention (out-proj writes d_out pair directly) ----
  k_ln<<<PT / 4, 256, 0, stream>>>(pair_f, ln_b, tri_ng, tri_nb, DP_);
  k_gemm64<2,0><<<dim3(6, 1024), 256, 0, stream>>>(ln_b, tri_qkv_wt, tri_qkv_b, nullptr, qkv_bf, nullptr, nullptr, PT, 384, DP_, 1.f);
  k_attn_mfma<256,2><<<dim3(L_, HT_, 2), 256, 0, stream>>>(qkv_bf, ao_b, DP_, 384, L_ * 384, DP_, L_ * DP_, scale);
  k_gemm64<4,0><<<dim3(2, 1024), 256, 0, stream>>>(ao_b, tri_out_wt, tri_out_b, dout_pair, nullptr, pair_f, nullptr, PT, DP_, DP_, 1.f);
}

// Round 19
// 428.820 us; speedup vs baseline: 1.0261x; 1.0261x over previous
//
#include <hip/hip_runtime.h>
#include <hip/hip_bf16.h>

// MSA Transformer block: B=1, S=64, L=256, DM=256, DP=128, H=8, HT=4, NO=32
// Round 19: revert r18's attn z-split regression (ZSP=1 everywhere = r17 path);
// keep OPM xor-shift swizzle (time-neutral, fewer conflicts). Best-known config.

#define S_ 64
#define L_ 256
#define DM_ 256
#define DP_ 128
#define H_ 8
#define HT_ 4
#define NO_ 32

typedef __hip_bfloat16 bf16;
typedef short short4s __attribute__((ext_vector_type(4)));
typedef short short8 __attribute__((ext_vector_type(8)));
typedef float floatx4 __attribute__((ext_vector_type(4)));

__device__ __forceinline__ short f2bfs(float x) {
  union { float f; unsigned u; } v;
  v.f = x;
  unsigned r = (v.u + 0x7fffu + ((v.u >> 16) & 1u)) >> 16;
  return (short)r;
}

// ---------------- layernorm (4 rows per 256-thr block, 1 wave per row) ----------------
__global__ void k_ln(const float* __restrict__ src, bf16* __restrict__ dst,
                     const float* __restrict__ g, const float* __restrict__ bta, int D) {
  int row = blockIdx.x * 4 + (threadIdx.x >> 6);
  const float* x = src + (size_t)row * D;
  bf16* y = dst + (size_t)row * D;
  int t = threadIdx.x & 63;
  float v[4];
  int cnt = 0;
  float sum = 0.f;
  for (int e = t; e < D; e += 64) { float xv = x[e]; v[cnt++] = xv; sum += xv; }
  #pragma unroll
  for (int o = 32; o; o >>= 1) sum += __shfl_down(sum, o);
  sum = __shfl(sum, 0);
  float mean = sum / D;
  float var = 0.f;
  for (int k = 0; k < cnt; k++) { float d = v[k] - mean; var += d * d; }
  #pragma unroll
  for (int o = 32; o; o >>= 1) var += __shfl_down(var, o);
  var = __shfl(var, 0);
  float rstd = rsqrtf(var / D + 1e-5f);
  cnt = 0;
  for (int e = t; e < D; e += 64)
    y[e] = __float2bfloat16((v[cnt++] - mean) * rstd * g[e] + bta[e]);
}

// ---------------- fused weight transpose: 10 jobs, one launch ----------------
struct WtJob { const float* W; bf16* Wt; int K; int N; int nblk; };
struct WtJobs { WtJob j[10]; };

__global__ void k_wt_all(WtJobs jobs) {
  __shared__ float tile[32][33];
  int b = blockIdx.x;
  int ji = 0;
  while (ji < 9 && b >= jobs.j[ji].nblk) { b -= jobs.j[ji].nblk; ji++; }
  const float* W = jobs.j[ji].W;
  bf16* Wt = jobs.j[ji].Wt;
  int K = jobs.j[ji].K, N = jobs.j[ji].N;
  int kt = K >> 5;
  int k0 = (b % kt) * 32, n0 = (b / kt) * 32;
  int tid = threadIdx.x; // 256
  for (int e = tid; e < 1024; e += 256) {
    int r = e >> 5, c = e & 31;
    tile[r][c] = W[(size_t)(k0 + r) * N + (n0 + c)];
  }
  __syncthreads();
  for (int e = tid; e < 1024; e += 256) {
    int r = e >> 5, c = e & 31;
    Wt[(size_t)(n0 + r) * K + (k0 + c)] = __float2bfloat16(tile[c][r]);
  }
}

// ---------------- OPM proj weight permute + ab-bias concat ----------------
__global__ void k_wtopm(const float* __restrict__ W, bf16* __restrict__ Wt,
                        const float* __restrict__ ba, const float* __restrict__ bb,
                        float* __restrict__ bias_ab) {
  if (blockIdx.x == 0 && threadIdx.x < 64)
    bias_ab[threadIdx.x] = threadIdx.x < 32 ? ba[threadIdx.x] : bb[threadIdx.x - 32];
  int idx = blockIdx.x * 256 + threadIdx.x; // 131072
  int d = idx >> 10, kk = idx & 1023;
  int e = kk >> 5, c = kk & 31;
  Wt[idx] = __float2bfloat16(W[(size_t)(c * 32 + e) * 128 + d]);
}

// ---------------- bf16 MFMA GEMM, 64x64 tile, optional fused LayerNorm ----------------
// MODE: 0 Cf=v | 1 Cf+=v | 2 Cb=bf16(v) | 3 Cb=bf16(relu v) | 4 Cf=Csrc+v
//       5 t=Cf+v; Cf=t; Cdup=t | 6 opm-ab: write transposed to a_t(Cb)/b_t(Cdup)
template<int MODE, int LNF>
__global__ void k_gemm64(const bf16* __restrict__ A, const bf16* __restrict__ Wt,
                         const float* __restrict__ bias, float* __restrict__ Cf,
                         bf16* __restrict__ Cb, const float* __restrict__ Csrc,
                         float* __restrict__ Cdup, int M, int N, int K, float scale,
                         const float* __restrict__ Af = nullptr,
                         const float* __restrict__ lng = nullptr,
                         const float* __restrict__ lnbt = nullptr) {
  __shared__ short As[64 * 64];
  __shared__ short Bs[64 * 64];
  __shared__ float sMean[64];
  __shared__ float sRstd[64];
  const int tid = threadIdx.x;
  const int nwg = gridDim.x * gridDim.y;
  const int wgid = blockIdx.y * gridDim.x + blockIdx.x;
  const int q = nwg >> 3, r8 = nwg & 7;
  const int xcd = wgid & 7, loc = wgid >> 3;
  const int swz = (xcd < r8 ? xcd * (q + 1) : r8 * (q + 1) + (xcd - r8) * q) + loc;
  const int by = swz / gridDim.x, bx = swz - by * gridDim.x;
  const int m0 = by * 64, n0 = bx * 64;
  const int w = tid >> 6, l = tid & 63;
  const int wm = (w >> 1) * 32, wn = (w & 1) * 32;
  const int lr = l & 15, lk = l >> 4;

  if (LNF) {
    int rr = tid >> 2, quad = tid & 3;
    const float* xr = Af + (size_t)(m0 + rr) * 256 + quad * 64;
    float s = 0.f, s2 = 0.f;
    #pragma unroll
    for (int ii = 0; ii < 16; ii++) {
      floatx4 x = *(const floatx4*)(xr + ii * 4);
      #pragma unroll
      for (int jj = 0; jj < 4; jj++) { s += x[jj]; s2 += x[jj] * x[jj]; }
    }
    #pragma unroll
    for (int o = 1; o <= 2; o <<= 1) { s += __shfl_xor(s, o); s2 += __shfl_xor(s2, o); }
    if (quad == 0) {
      float mean = s * 0.00390625f;
      float var = s2 * 0.00390625f - mean * mean;
      sMean[rr] = mean;
      sRstd[rr] = rsqrtf(var + 1e-5f);
    }
    __syncthreads();
  }

  floatx4 acc[2][2] = {};
  const short* Ash = (const short*)A;
  const short* Bsh = (const short*)Wt;
  for (int k0 = 0; k0 < K; k0 += 64) {
    if (LNF) {
      for (int e = tid; e < 512; e += 256) {
        int r = e >> 3, kg = e & 7;
        int kb = k0 + kg * 8;
        const float* src = Af + (size_t)(m0 + r) * 256 + kb;
        floatx4 x0 = *(const floatx4*)(src);
        floatx4 x1 = *(const floatx4*)(src + 4);
        float mean = sMean[r], rstd = sRstd[r];
        short8 v;
        #pragma unroll
        for (int jj = 0; jj < 4; jj++) {
          v[jj] = f2bfs((x0[jj] - mean) * rstd * lng[kb + jj] + lnbt[kb + jj]);
          v[jj + 4] = f2bfs((x1[jj] - mean) * rstd * lng[kb + 4 + jj] + lnbt[kb + 4 + jj]);
        }
        *(short8*)(&As[r * 64 + ((kg ^ (r & 7)) * 8)]) = v;
      }
    } else {
      for (int e = tid; e < 512; e += 256) {
        int r = e >> 3, kg = e & 7;
        short8 v = *(const short8*)(Ash + (size_t)(m0 + r) * K + k0 + kg * 8);
        *(short8*)(&As[r * 64 + ((kg ^ (r & 7)) * 8)]) = v;
      }
    }
    for (int e = tid; e < 512; e += 256) {
      int r = e >> 3, kg = e & 7;
      int n = n0 + r;
      short8 v = {0, 0, 0, 0, 0, 0, 0, 0};
      if (n < N) v = *(const short8*)(Bsh + (size_t)n * K + k0 + kg * 8);
      *(short8*)(&Bs[r * 64 + ((kg ^ (r & 7)) * 8)]) = v;
    }
    __syncthreads();
    #pragma unroll
    for (int kk = 0; kk < 2; kk++) {
      short8 af[2], bfr[2];
      #pragma unroll
      for (int mi = 0; mi < 2; mi++) {
        int row = wm + mi * 16 + lr;
        int kg = kk * 4 + lk;
        af[mi] = *(const short8*)(&As[row * 64 + ((kg ^ (row & 7)) * 8)]);
      }
      #pragma unroll
      for (int ni = 0; ni < 2; ni++) {
        int row = wn + ni * 16 + lr;
        int kg = kk * 4 + lk;
        bfr[ni] = *(const short8*)(&Bs[row * 64 + ((kg ^ (row & 7)) * 8)]);
      }
      #pragma unroll
      for (int mi = 0; mi < 2; mi++)
        #pragma unroll
        for (int ni = 0; ni < 2; ni++)
          acc[mi][ni] = __builtin_amdgcn_mfma_f32_16x16x32_bf16(af[mi], bfr[ni], acc[mi][ni], 0, 0, 0);
    }
    __syncthreads();
  }
  #pragma unroll
  for (int ni = 0; ni < 2; ni++) {
    int n = n0 + wn + ni * 16 + lr;
    if (n >= N) continue;
    float bv = bias ? bias[n] : 0.f;
    #pragma unroll
    for (int mi = 0; mi < 2; mi++) {
      int mbase = m0 + wm + mi * 16 + lk * 4;
      #pragma unroll
      for (int r = 0; r < 4; r++) {
        float v = acc[mi][ni][r] * scale + bv;
        size_t idx = (size_t)(mbase + r) * N + n;
        if (MODE == 0) Cf[idx] = v;
        else if (MODE == 1) Cf[idx] += v;
        else if (MODE == 2) Cb[idx] = __float2bfloat16(v);
        else if (MODE == 3) Cb[idx] = __float2bfloat16(fmaxf(v, 0.f));
        else if (MODE == 4) Cf[idx] = Csrc[idx] + v;
        else if (MODE == 5) { float t = Cf[idx] + v; Cf[idx] = t; Cdup[idx] = t; }
        else if (MODE == 6) {
          int m = mbase + r;
          int s = m >> 8, i2 = m & 255;
          int y = n >> 5, c = n & 31;
          bf16* outp = y ? (bf16*)Cdup : Cb;
          outp[((size_t)i2 * NO_ + c) * S_ + s] = __float2bfloat16(v);
        }
      }
    }
  }
}

// ---------------- fused OPM, 512 threads; U-slot xor-shift swizzle ----------------
__global__ __launch_bounds__(512) void k_opm_fused(
    const bf16* __restrict__ a_t, const bf16* __restrict__ b_t,
    const bf16* __restrict__ Wt, const float* __restrict__ bias,
    const float* __restrict__ pair_in, float* __restrict__ pair_out) {
  __shared__ short U[32 * 512]; // 32 KB
  const int i = blockIdx.y;
  const int jg = blockIdx.x; // 0..7
  const int tid = threadIdx.x;
  const int w = tid >> 6, l = tid & 63;   // w in 0..7
  const int lr = l & 15, lk = l >> 4;
  const short* at = (const short*)a_t;
  const short* bt = (const short*)b_t;
  const short* wt = (const short*)Wt;

  short8 af[2][2];
  #pragma unroll
  for (int kh = 0; kh < 2; kh++)
    #pragma unroll
    for (int ks = 0; ks < 2; ks++)
      af[kh][ks] = *(const short8*)(at + ((size_t)i * 32 + kh * 16 + lr) * 64 + ks * 32 + lk * 8);

  floatx4 pacc[2] = {};
  #pragma unroll
  for (int kh = 0; kh < 2; kh++) {
    #pragma unroll
    for (int sc = 0; sc < 2; sc++) {
      floatx4 uacc[4] = {};
      const size_t rowbase = ((size_t)(jg * 32 + sc * 16) << 5) + w * 64;
      #pragma unroll
      for (int ks = 0; ks < 2; ks++)
        #pragma unroll
        for (int nt = 0; nt < 4; nt++) {
          short8 bfr = *(const short8*)(bt + (rowbase + nt * 16 + lr) * 64 + ks * 32 + lk * 8);
          uacc[nt] = __builtin_amdgcn_mfma_f32_16x16x32_bf16(af[kh][ks], bfr, uacc[nt], 0, 0, 0);
        }
      #pragma unroll
      for (int nt = 0; nt < 4; nt++) {
        int npos = w * 64 + nt * 16 + lr;
        int jj = sc * 16 + (npos >> 5);
        int e = npos & 31;
        int g = e * 2 + (lk >> 1);
        int sg = (g ^ (g >> 3)) ^ (jj & 7);
        int off = (lk & 1) * 4;
        short4s pk;
        pk.x = f2bfs(uacc[nt][0] * 0.015625f);
        pk.y = f2bfs(uacc[nt][1] * 0.015625f);
        pk.z = f2bfs(uacc[nt][2] * 0.015625f);
        pk.w = f2bfs(uacc[nt][3] * 0.015625f);
        *(short4s*)(&U[jj * 512 + (sg << 3) + off]) = pk;
      }
    }
    __syncthreads();
    #pragma unroll 4
    for (int ks = 0; ks < 16; ks++) {
      short8 afp[2];
      #pragma unroll
      for (int mt = 0; mt < 2; mt++) {
        int row = mt * 16 + lr;
        int g = ks * 4 + lk;
        int sg = (g ^ (g >> 3)) ^ (row & 7);
        afp[mt] = *(const short8*)(&U[row * 512 + (sg << 3)]);
      }
      int wko = (ks * 2 + (lk >> 1)) * 32 + kh * 16 + (lk & 1) * 8;
      int d = w * 16 + lr;
      short8 bfr = *(const short8*)(wt + (size_t)d * 1024 + wko);
      #pragma unroll
      for (int mt = 0; mt < 2; mt++)
        pacc[mt] = __builtin_amdgcn_mfma_f32_16x16x32_bf16(afp[mt], bfr, pacc[mt], 0, 0, 0);
    }
    __syncthreads();
  }
  int jbase = jg * 32;
  int d = w * 16 + lr;
  float bv = bias[d];
  #pragma unroll
  for (int mt = 0; mt < 2; mt++)
    #pragma unroll
    for (int r = 0; r < 4; r++) {
      int j = jbase + mt * 16 + lk * 4 + r;
      size_t idx = ((size_t)i * L_ + j) * DP_ + d;
      pair_out[idx] = pair_in[idx] + pacc[mt][r] + bv;
    }
}

// ---------------- MFMA attention: one (lead, head) per block; K/V staged once ----------------
template<int N>
__global__ __launch_bounds__(256) void k_attn_mfma(
    const bf16* __restrict__ qkv, bf16* __restrict__ out, int dmodel,
    int tokStride, int leadStride, int otokStride, int oleadStride, float scale) {
  constexpr int NT = N / 16;
  constexpr int NK = N / 32;
  constexpr int NIC = N / 64;
  __shared__ short Ks[N * 32];
  __shared__ short Vt[N * 32];
  __shared__ short Qs[2048];
  __shared__ short P[64 * N];

  const int lead = blockIdx.x;
  const int h = blockIdx.y;
  const short* base = (const short*)qkv + (size_t)lead * leadStride;
  const int qoff = h * 32, koff = dmodel + h * 32, voff = 2 * dmodel + h * 32;
  const int tid = threadIdx.x;
  const int l = tid & 63, w = tid >> 6;
  const int lr = l & 15, lk = l >> 4;

  for (int e = tid; e < N * 4; e += 256) {
    int j = e >> 2, kg = e & 3;
    short8 v = *(const short8*)(base + (size_t)j * tokStride + koff + kg * 8);
    *(short8*)(&Ks[(kg * N + j) * 8]) = v;
  }
  for (int e = tid; e < N * 32; e += 256) {
    int j = e >> 5, d = e & 31;
    Vt[((j >> 5) * 4 + ((j >> 3) & 3)) * 256 + d * 8 + (j & 7)] = base[(size_t)j * tokStride + voff + d];
  }
  __syncthreads();

  for (int ic = 0; ic < NIC; ic++) {
    {
      int r = tid >> 2, kg = tid & 3;
      short8 v = *(const short8*)(base + (size_t)(ic * 64 + r) * tokStride + qoff + kg * 8);
      *(short8*)(&Qs[(kg * 64 + r) * 8]) = v;
    }
    short8 aq = *(const short8*)(&Qs[(lk * 64 + w * 16 + lr) * 8]);
    floatx4 sa[NT];
    #pragma unroll
    for (int t = 0; t < NT; t++) {
      short8 bk = *(const short8*)(&Ks[(lk * N + t * 16 + lr) * 8]);
      floatx4 z = {0.f, 0.f, 0.f, 0.f};
      sa[t] = __builtin_amdgcn_mfma_f32_16x16x32_bf16(aq, bk, z, 0, 0, 0);
    }

    float mrow[4] = {-1e30f, -1e30f, -1e30f, -1e30f};
    #pragma unroll
    for (int t = 0; t < NT; t++)
      #pragma unroll
      for (int r = 0; r < 4; r++) {
        float s = fminf(fmaxf(sa[t][r] * scale, -50.f), 50.f);
        sa[t][r] = s;
        mrow[r] = fmaxf(mrow[r], s);
      }
    #pragma unroll
    for (int o = 1; o <= 8; o <<= 1)
      #pragma unroll
      for (int r = 0; r < 4; r++) mrow[r] = fmaxf(mrow[r], __shfl_xor(mrow[r], o));
    float srow[4] = {0.f, 0.f, 0.f, 0.f};
    #pragma unroll
    for (int t = 0; t < NT; t++)
      #pragma unroll
      for (int r = 0; r < 4; r++) {
        float p = __expf(sa[t][r] - mrow[r]);
        sa[t][r] = p;
        srow[r] += p;
      }
    #pragma unroll
    for (int o = 1; o <= 8; o <<= 1)
      #pragma unroll
      for (int r = 0; r < 4; r++) srow[r] += __shfl_xor(srow[r], o);
    float inv[4];
    #pragma unroll
    for (int r = 0; r < 4; r++) inv[r] = 1.f / srow[r];

    #pragma unroll
    for (int t = 0; t < NT; t++) {
      int c = t * 16 + lr;
      int kstep = c >> 5, kslot = (c >> 3) & 3, u = c & 7;
      #pragma unroll
      for (int r = 0; r < 4; r++) {
        int row = w * 16 + lk * 4 + r;
        P[((kstep * 4 + kslot) * 64 + row) * 8 + u] = f2bfs(sa[t][r] * inv[r]);
      }
    }

    floatx4 oacc[2] = {{0.f,0.f,0.f,0.f},{0.f,0.f,0.f,0.f}};
    #pragma unroll
    for (int ks = 0; ks < NK; ks++) {
      short8 ap = *(const short8*)(&P[((ks * 4 + lk) * 64 + w * 16 + lr) * 8]);
      #pragma unroll
      for (int ct = 0; ct < 2; ct++) {
        short8 bv = *(const short8*)(&Vt[((ks * 4 + lk) * 32 + ct * 16 + lr) * 8]);
        oacc[ct] = __builtin_amdgcn_mfma_f32_16x16x32_bf16(ap, bv, oacc[ct], 0, 0, 0);
      }
    }
    bf16* ob = out + (size_t)lead * oleadStride + h * 32;
    #pragma unroll
    for (int ct = 0; ct < 2; ct++)
      #pragma unroll
      for (int r = 0; r < 4; r++) {
        int tok = ic * 64 + w * 16 + lk * 4 + r;
        ob[(size_t)tok * otokStride + ct * 16 + lr] = __float2bfloat16(oacc[ct][r]);
      }
  }
}

extern "C" void kernel_launch(void* const* d_in, const int* in_sizes, int n_in,
                              void* d_out, int out_size, void* d_ws, size_t ws_size,
                              hipStream_t stream) {
  const float* msa_in    = (const float*)d_in[0];
  const float* pair_in   = (const float*)d_in[1];
  const float* row_ng    = (const float*)d_in[2];
  const float* row_nb    = (const float*)d_in[3];
  const float* row_qkv_w = (const float*)d_in[4];
  const float* row_qkv_b = (const float*)d_in[5];
  const float* row_out_w = (const float*)d_in[6];
  const float* row_out_b = (const float*)d_in[7];
  const float* col_ng    = (const float*)d_in[8];
  const float* col_nb    = (const float*)d_in[9];
  const float* col_qkv_w = (const float*)d_in[10];
  const float* col_qkv_b = (const float*)d_in[11];
  const float* col_out_w = (const float*)d_in[12];
  const float* col_out_b = (const float*)d_in[13];
  const float* ff_ng     = (const float*)d_in[14];
  const float* ff_nb     = (const float*)d_in[15];
  const float* ff_w1     = (const float*)d_in[16];
  const float* ff_b1     = (const float*)d_in[17];
  const float* ff_w2     = (const float*)d_in[18];
  const float* ff_b2     = (const float*)d_in[19];
  const float* op_ng     = (const float*)d_in[20];
  const float* op_nb     = (const float*)d_in[21];
  const float* op_a_w    = (const float*)d_in[22];
  const float* op_a_b    = (const float*)d_in[23];
  const float* op_b_w    = (const float*)d_in[24];
  const float* op_b_b    = (const float*)d_in[25];
  const float* op_out_w  = (const float*)d_in[26];
  const float* op_out_b  = (const float*)d_in[27];
  const float* tri_ng    = (const float*)d_in[28];
  const float* tri_nb    = (const float*)d_in[29];
  const float* tri_qkv_w = (const float*)d_in[30];
  const float* tri_qkv_b = (const float*)d_in[31];
  const float* tri_out_w = (const float*)d_in[32];
  const float* tri_out_b = (const float*)d_in[33];

  const int MT = S_ * L_;   // 16384
  const int PT = L_ * L_;   // 65536

  // ---- arena (byte offsets) ----
  char* ws = (char*)d_ws;
  float* msa_f  = (float*)(ws);                    // 16 MB
  float* pair_f = (float*)(ws + 16777216);         // 32 MB
  char*  X      = ws + 50331648;                   // 48 MB scratch (qkv bf16 / ffh bf16)
  bf16*  ln_b   = (bf16*)(ws + 100663296);         // 16 MB
  bf16*  ao_b   = (bf16*)(ws + 117440512);         // 16 MB
  bf16*  a_t    = (bf16*)(ws + 136314880);         // 1 MB
  bf16*  b_t    = (bf16*)(ws + 137363456);         // 1 MB
  bf16*  wts    = (bf16*)(ws + 138412032);         // ~2.6 MB
  float* bias_ab = (float*)(ws + 141557760);       // 64 floats

  bf16* row_qkv_wt = wts;                 // 768*256
  bf16* col_qkv_wt = row_qkv_wt + 196608;
  bf16* row_out_wt = col_qkv_wt + 196608; // 256*256
  bf16* col_out_wt = row_out_wt + 65536;
  bf16* ff_w1t     = col_out_wt + 65536;  // 1024*256
  bf16* ff_w2t     = ff_w1t + 262144;     // 256*1024
  bf16* op_ab_wt   = ff_w2t + 262144;     // 64*256
  bf16* op_out_wt  = op_ab_wt + 16384;    // 128*1024 (ec-permuted)
  bf16* tri_qkv_wt = op_out_wt + 131072;  // 384*128
  bf16* tri_out_wt = tri_qkv_wt + 49152;  // 128*128

  bf16* qkv_bf = (bf16*)X;
  bf16* ffh    = (bf16*)X;

  float* dout_msa  = (float*)d_out;
  float* dout_pair = (float*)d_out + (size_t)MT * DM_;

  const float scale = 0.17677669529663687f; // 1/sqrt(32)

  // ---- weight prep: 2 launches total ----
  WtJobs jobs;
  jobs.j[0] = {row_qkv_w, row_qkv_wt, 256, 768, 192};
  jobs.j[1] = {col_qkv_w, col_qkv_wt, 256, 768, 192};
  jobs.j[2] = {row_out_w, row_out_wt, 256, 256, 64};
  jobs.j[3] = {col_out_w, col_out_wt, 256, 256, 64};
  jobs.j[4] = {ff_w1, ff_w1t, 256, 1024, 256};
  jobs.j[5] = {ff_w2, ff_w2t, 1024, 256, 256};
  jobs.j[6] = {op_a_w, op_ab_wt, 256, 32, 8};
  jobs.j[7] = {op_b_w, op_ab_wt + 32 * 256, 256, 32, 8};
  jobs.j[8] = {tri_qkv_w, tri_qkv_wt, 128, 384, 48};
  jobs.j[9] = {tri_out_w, tri_out_wt, 128, 128, 16};
  k_wt_all<<<1104, 256, 0, stream>>>(jobs);
  k_wtopm<<<512, 256, 0, stream>>>(op_out_w, op_out_wt, op_a_b, op_b_b, bias_ab);

  // ---- 1. row attention (attend over L) ----
  k_ln<<<MT / 4, 256, 0, stream>>>(msa_in, ln_b, row_ng, row_nb, DM_);
  k_gemm64<2,0><<<dim3(12, 256), 256, 0, stream>>>(ln_b, row_qkv_wt, row_qkv_b, nullptr, qkv_bf, nullptr, nullptr, MT, 768, 256, 1.f);
  k_attn_mfma<256><<<dim3(S_, H_), 256, 0, stream>>>(qkv_bf, ao_b, DM_, 768, L_ * 768, DM_, L_ * DM_, scale);
  k_gemm64<4,0><<<dim3(4, 256), 256, 0, stream>>>(ao_b, row_out_wt, row_out_b, msa_f, nullptr, msa_in, nullptr, MT, DM_, DM_, 1.f);

  // ---- 2. column attention (attend over S) ----
  k_ln<<<MT / 4, 256, 0, stream>>>(msa_f, ln_b, col_ng, col_nb, DM_);
  k_gemm64<2,0><<<dim3(12, 256), 256, 0, stream>>>(ln_b, col_qkv_wt, col_qkv_b, nullptr, qkv_bf, nullptr, nullptr, MT, 768, 256, 1.f);
  k_attn_mfma<64><<<dim3(L_, H_), 256, 0, stream>>>(qkv_bf, ao_b, DM_, L_ * 768, 768, L_ * DM_, DM_, scale);
  k_gemm64<1,0><<<dim3(4, 256), 256, 0, stream>>>(ao_b, col_out_wt, col_out_b, msa_f, nullptr, nullptr, nullptr, MT, DM_, DM_, 1.f);

  // ---- 3. feed-forward (down-proj also writes d_out msa) ----
  k_ln<<<MT / 4, 256, 0, stream>>>(msa_f, ln_b, ff_ng, ff_nb, DM_);
  k_gemm64<3,0><<<dim3(16, 256), 256, 0, stream>>>(ln_b, ff_w1t, ff_b1, nullptr, ffh, nullptr, nullptr, MT, 1024, 256, 1.f);
  k_gemm64<5,0><<<dim3(4, 256), 256, 0, stream>>>(ffh, ff_w2t, ff_b2, msa_f, nullptr, nullptr, dout_msa, MT, DM_, 1024, 1.f);

  // ---- 4. outer product mean -> pair (LN fused; transposed write; grid.x==1) ----
  k_gemm64<6,1><<<dim3(1, 256), 256, 0, stream>>>(nullptr, op_ab_wt, bias_ab, nullptr, a_t, nullptr, (float*)b_t, MT, 64, 256, 1.f, msa_f, op_ng, op_nb);
  k_opm_fused<<<dim3(8, L_), 512, 0, stream>>>(a_t, b_t, op_out_wt, op_out_b, pair_in, pair_f);

  // ---- 5. triangle attention (out-proj writes d_out pair directly) ----
  k_ln<<<PT / 4, 256, 0, stream>>>(pair_f, ln_b, tri_ng, tri_nb, DP_);
  k_gemm64<2,0><<<dim3(6, 1024), 256, 0, stream>>>(ln_b, tri_qkv_wt, tri_qkv_b, nullptr, qkv_bf, nullptr, nullptr, PT, 384, DP_, 1.f);
  k_attn_mfma<256><<<dim3(L_, HT_), 256, 0, stream>>>(qkv_bf, ao_b, DP_, 384, L_ * 384, DP_, L_ * DP_, scale);
  k_gemm64<4,0><<<dim3(2, 1024), 256, 0, stream>>>(ao_b, tri_out_wt, tri_out_b, dout_pair, nullptr, pair_f, nullptr, PT, DP_, DP_, 1.f);
}

// Round 20
// 425.513 us; speedup vs baseline: 1.0341x; 1.0078x over previous
//
#include <hip/hip_runtime.h>
#include <hip/hip_bf16.h>

// MSA Transformer block: B=1, S=64, L=256, DM=256, DP=128, H=8, HT=4, NO=32
// Round 20: dispatch trims — weight prep in ONE launch (11 jobs incl. OPM
// permute), OPM trailing barrier removed. Numerics identical to r19.

#define S_ 64
#define L_ 256
#define DM_ 256
#define DP_ 128
#define H_ 8
#define HT_ 4
#define NO_ 32

typedef __hip_bfloat16 bf16;
typedef short short4s __attribute__((ext_vector_type(4)));
typedef short short8 __attribute__((ext_vector_type(8)));
typedef float floatx4 __attribute__((ext_vector_type(4)));

__device__ __forceinline__ short f2bfs(float x) {
  union { float f; unsigned u; } v;
  v.f = x;
  unsigned r = (v.u + 0x7fffu + ((v.u >> 16) & 1u)) >> 16;
  return (short)r;
}

// ---------------- layernorm (4 rows per 256-thr block, 1 wave per row) ----------------
__global__ void k_ln(const float* __restrict__ src, bf16* __restrict__ dst,
                     const float* __restrict__ g, const float* __restrict__ bta, int D) {
  int row = blockIdx.x * 4 + (threadIdx.x >> 6);
  const float* x = src + (size_t)row * D;
  bf16* y = dst + (size_t)row * D;
  int t = threadIdx.x & 63;
  float v[4];
  int cnt = 0;
  float sum = 0.f;
  for (int e = t; e < D; e += 64) { float xv = x[e]; v[cnt++] = xv; sum += xv; }
  #pragma unroll
  for (int o = 32; o; o >>= 1) sum += __shfl_down(sum, o);
  sum = __shfl(sum, 0);
  float mean = sum / D;
  float var = 0.f;
  for (int k = 0; k < cnt; k++) { float d = v[k] - mean; var += d * d; }
  #pragma unroll
  for (int o = 32; o; o >>= 1) var += __shfl_down(var, o);
  var = __shfl(var, 0);
  float rstd = rsqrtf(var / D + 1e-5f);
  cnt = 0;
  for (int e = t; e < D; e += 64)
    y[e] = __float2bfloat16((v[cnt++] - mean) * rstd * g[e] + bta[e]);
}

// ---------------- weight prep: 11 jobs (10 transpose + 1 OPM permute), ONE launch ----------------
struct WtJob { const float* W; bf16* Wt; int K; int N; int nblk; };
struct WtJobs {
  WtJob j[10];
  const float* opW; bf16* opWt;              // OPM permute job (512 blocks)
  const float* ba; const float* bb; float* bias_ab;
};

__global__ void k_wt_all(WtJobs jobs) {
  __shared__ float tile[32][33];
  int b = blockIdx.x;
  // jobs 0..9: 32x32 transpose tiles
  int ji = 0;
  while (ji < 10 && b >= jobs.j[ji].nblk) { b -= jobs.j[ji].nblk; ji++; }
  if (ji < 10) {
    const float* W = jobs.j[ji].W;
    bf16* Wt = jobs.j[ji].Wt;
    int K = jobs.j[ji].K, N = jobs.j[ji].N;
    int kt = K >> 5;
    int k0 = (b % kt) * 32, n0 = (b / kt) * 32;
    int tid = threadIdx.x; // 256
    for (int e = tid; e < 1024; e += 256) {
      int r = e >> 5, c = e & 31;
      tile[r][c] = W[(size_t)(k0 + r) * N + (n0 + c)];
    }
    __syncthreads();
    for (int e = tid; e < 1024; e += 256) {
      int r = e >> 5, c = e & 31;
      Wt[(size_t)(n0 + r) * K + (k0 + c)] = __float2bfloat16(tile[c][r]);
    }
    return;
  }
  // OPM permute job: 512 blocks
  if (b == 0 && threadIdx.x < 64)
    jobs.bias_ab[threadIdx.x] = threadIdx.x < 32 ? jobs.ba[threadIdx.x] : jobs.bb[threadIdx.x - 32];
  int idx = b * 256 + threadIdx.x; // 131072
  int d = idx >> 10, kk = idx & 1023;
  int e = kk >> 5, c = kk & 31;
  jobs.opWt[idx] = __float2bfloat16(jobs.opW[(size_t)(c * 32 + e) * 128 + d]);
}

// ---------------- bf16 MFMA GEMM, 64x64 tile, optional fused LayerNorm ----------------
// MODE: 0 Cf=v | 1 Cf+=v | 2 Cb=bf16(v) | 3 Cb=bf16(relu v) | 4 Cf=Csrc+v
//       5 t=Cf+v; Cf=t; Cdup=t | 6 opm-ab: write transposed to a_t(Cb)/b_t(Cdup)
template<int MODE, int LNF>
__global__ void k_gemm64(const bf16* __restrict__ A, const bf16* __restrict__ Wt,
                         const float* __restrict__ bias, float* __restrict__ Cf,
                         bf16* __restrict__ Cb, const float* __restrict__ Csrc,
                         float* __restrict__ Cdup, int M, int N, int K, float scale,
                         const float* __restrict__ Af = nullptr,
                         const float* __restrict__ lng = nullptr,
                         const float* __restrict__ lnbt = nullptr) {
  __shared__ short As[64 * 64];
  __shared__ short Bs[64 * 64];
  __shared__ float sStats[LNF ? 128 : 2];  // mean[64] + rstd[64] when LNF
  const int tid = threadIdx.x;
  const int nwg = gridDim.x * gridDim.y;
  const int wgid = blockIdx.y * gridDim.x + blockIdx.x;
  const int q = nwg >> 3, r8 = nwg & 7;
  const int xcd = wgid & 7, loc = wgid >> 3;
  const int swz = (xcd < r8 ? xcd * (q + 1) : r8 * (q + 1) + (xcd - r8) * q) + loc;
  const int by = swz / gridDim.x, bx = swz - by * gridDim.x;
  const int m0 = by * 64, n0 = bx * 64;
  const int w = tid >> 6, l = tid & 63;
  const int wm = (w >> 1) * 32, wn = (w & 1) * 32;
  const int lr = l & 15, lk = l >> 4;

  if (LNF) {
    int rr = tid >> 2, quad = tid & 3;
    const float* xr = Af + (size_t)(m0 + rr) * 256 + quad * 64;
    float s = 0.f, s2 = 0.f;
    #pragma unroll
    for (int ii = 0; ii < 16; ii++) {
      floatx4 x = *(const floatx4*)(xr + ii * 4);
      #pragma unroll
      for (int jj = 0; jj < 4; jj++) { s += x[jj]; s2 += x[jj] * x[jj]; }
    }
    #pragma unroll
    for (int o = 1; o <= 2; o <<= 1) { s += __shfl_xor(s, o); s2 += __shfl_xor(s2, o); }
    if (quad == 0) {
      float mean = s * 0.00390625f;
      float var = s2 * 0.00390625f - mean * mean;
      sStats[rr] = mean;
      sStats[64 + rr] = rsqrtf(var + 1e-5f);
    }
    __syncthreads();
  }

  floatx4 acc[2][2] = {};
  const short* Ash = (const short*)A;
  const short* Bsh = (const short*)Wt;
  for (int k0 = 0; k0 < K; k0 += 64) {
    if (LNF) {
      for (int e = tid; e < 512; e += 256) {
        int r = e >> 3, kg = e & 7;
        int kb = k0 + kg * 8;
        const float* src = Af + (size_t)(m0 + r) * 256 + kb;
        floatx4 x0 = *(const floatx4*)(src);
        floatx4 x1 = *(const floatx4*)(src + 4);
        float mean = sStats[r], rstd = sStats[64 + r];
        short8 v;
        #pragma unroll
        for (int jj = 0; jj < 4; jj++) {
          v[jj] = f2bfs((x0[jj] - mean) * rstd * lng[kb + jj] + lnbt[kb + jj]);
          v[jj + 4] = f2bfs((x1[jj] - mean) * rstd * lng[kb + 4 + jj] + lnbt[kb + 4 + jj]);
        }
        *(short8*)(&As[r * 64 + ((kg ^ (r & 7)) * 8)]) = v;
      }
    } else {
      for (int e = tid; e < 512; e += 256) {
        int r = e >> 3, kg = e & 7;
        short8 v = *(const short8*)(Ash + (size_t)(m0 + r) * K + k0 + kg * 8);
        *(short8*)(&As[r * 64 + ((kg ^ (r & 7)) * 8)]) = v;
      }
    }
    for (int e = tid; e < 512; e += 256) {
      int r = e >> 3, kg = e & 7;
      int n = n0 + r;
      short8 v = {0, 0, 0, 0, 0, 0, 0, 0};
      if (n < N) v = *(const short8*)(Bsh + (size_t)n * K + k0 + kg * 8);
      *(short8*)(&Bs[r * 64 + ((kg ^ (r & 7)) * 8)]) = v;
    }
    __syncthreads();
    #pragma unroll
    for (int kk = 0; kk < 2; kk++) {
      short8 af[2], bfr[2];
      #pragma unroll
      for (int mi = 0; mi < 2; mi++) {
        int row = wm + mi * 16 + lr;
        int kg = kk * 4 + lk;
        af[mi] = *(const short8*)(&As[row * 64 + ((kg ^ (row & 7)) * 8)]);
      }
      #pragma unroll
      for (int ni = 0; ni < 2; ni++) {
        int row = wn + ni * 16 + lr;
        int kg = kk * 4 + lk;
        bfr[ni] = *(const short8*)(&Bs[row * 64 + ((kg ^ (row & 7)) * 8)]);
      }
      #pragma unroll
      for (int mi = 0; mi < 2; mi++)
        #pragma unroll
        for (int ni = 0; ni < 2; ni++)
          acc[mi][ni] = __builtin_amdgcn_mfma_f32_16x16x32_bf16(af[mi], bfr[ni], acc[mi][ni], 0, 0, 0);
    }
    __syncthreads();
  }
  #pragma unroll
  for (int ni = 0; ni < 2; ni++) {
    int n = n0 + wn + ni * 16 + lr;
    if (n >= N) continue;
    float bv = bias ? bias[n] : 0.f;
    #pragma unroll
    for (int mi = 0; mi < 2; mi++) {
      int mbase = m0 + wm + mi * 16 + lk * 4;
      #pragma unroll
      for (int r = 0; r < 4; r++) {
        float v = acc[mi][ni][r] * scale + bv;
        size_t idx = (size_t)(mbase + r) * N + n;
        if (MODE == 0) Cf[idx] = v;
        else if (MODE == 1) Cf[idx] += v;
        else if (MODE == 2) Cb[idx] = __float2bfloat16(v);
        else if (MODE == 3) Cb[idx] = __float2bfloat16(fmaxf(v, 0.f));
        else if (MODE == 4) Cf[idx] = Csrc[idx] + v;
        else if (MODE == 5) { float t = Cf[idx] + v; Cf[idx] = t; Cdup[idx] = t; }
        else if (MODE == 6) {
          int m = mbase + r;
          int s = m >> 8, i2 = m & 255;
          int y = n >> 5, c = n & 31;
          bf16* outp = y ? (bf16*)Cdup : Cb;
          outp[((size_t)i2 * NO_ + c) * S_ + s] = __float2bfloat16(v);
        }
      }
    }
  }
}

// ---------------- fused OPM, 512 threads; xor-shift swizzle; no trailing barrier ----------------
__global__ __launch_bounds__(512) void k_opm_fused(
    const bf16* __restrict__ a_t, const bf16* __restrict__ b_t,
    const bf16* __restrict__ Wt, const float* __restrict__ bias,
    const float* __restrict__ pair_in, float* __restrict__ pair_out) {
  __shared__ short U[32 * 512]; // 32 KB
  const int i = blockIdx.y;
  const int jg = blockIdx.x; // 0..7
  const int tid = threadIdx.x;
  const int w = tid >> 6, l = tid & 63;   // w in 0..7
  const int lr = l & 15, lk = l >> 4;
  const short* at = (const short*)a_t;
  const short* bt = (const short*)b_t;
  const short* wt = (const short*)Wt;

  short8 af[2][2];
  #pragma unroll
  for (int kh = 0; kh < 2; kh++)
    #pragma unroll
    for (int ks = 0; ks < 2; ks++)
      af[kh][ks] = *(const short8*)(at + ((size_t)i * 32 + kh * 16 + lr) * 64 + ks * 32 + lk * 8);

  floatx4 pacc[2] = {};
  #pragma unroll
  for (int kh = 0; kh < 2; kh++) {
    #pragma unroll
    for (int sc = 0; sc < 2; sc++) {
      floatx4 uacc[4] = {};
      const size_t rowbase = ((size_t)(jg * 32 + sc * 16) << 5) + w * 64;
      #pragma unroll
      for (int ks = 0; ks < 2; ks++)
        #pragma unroll
        for (int nt = 0; nt < 4; nt++) {
          short8 bfr = *(const short8*)(bt + (rowbase + nt * 16 + lr) * 64 + ks * 32 + lk * 8);
          uacc[nt] = __builtin_amdgcn_mfma_f32_16x16x32_bf16(af[kh][ks], bfr, uacc[nt], 0, 0, 0);
        }
      #pragma unroll
      for (int nt = 0; nt < 4; nt++) {
        int npos = w * 64 + nt * 16 + lr;
        int jj = sc * 16 + (npos >> 5);
        int e = npos & 31;
        int g = e * 2 + (lk >> 1);
        int sg = (g ^ (g >> 3)) ^ (jj & 7);
        int off = (lk & 1) * 4;
        short4s pk;
        pk.x = f2bfs(uacc[nt][0] * 0.015625f);
        pk.y = f2bfs(uacc[nt][1] * 0.015625f);
        pk.z = f2bfs(uacc[nt][2] * 0.015625f);
        pk.w = f2bfs(uacc[nt][3] * 0.015625f);
        *(short4s*)(&U[jj * 512 + (sg << 3) + off]) = pk;
      }
    }
    __syncthreads();
    #pragma unroll 4
    for (int ks = 0; ks < 16; ks++) {
      short8 afp[2];
      #pragma unroll
      for (int mt = 0; mt < 2; mt++) {
        int row = mt * 16 + lr;
        int g = ks * 4 + lk;
        int sg = (g ^ (g >> 3)) ^ (row & 7);
        afp[mt] = *(const short8*)(&U[row * 512 + (sg << 3)]);
      }
      int wko = (ks * 2 + (lk >> 1)) * 32 + kh * 16 + (lk & 1) * 8;
      int d = w * 16 + lr;
      short8 bfr = *(const short8*)(wt + (size_t)d * 1024 + wko);
      #pragma unroll
      for (int mt = 0; mt < 2; mt++)
        pacc[mt] = __builtin_amdgcn_mfma_f32_16x16x32_bf16(afp[mt], bfr, pacc[mt], 0, 0, 0);
    }
    if (kh == 0) __syncthreads();   // only needed before kh=1 overwrites U
  }
  int jbase = jg * 32;
  int d = w * 16 + lr;
  float bv = bias[d];
  #pragma unroll
  for (int mt = 0; mt < 2; mt++)
    #pragma unroll
    for (int r = 0; r < 4; r++) {
      int j = jbase + mt * 16 + lk * 4 + r;
      size_t idx = ((size_t)i * L_ + j) * DP_ + d;
      pair_out[idx] = pair_in[idx] + pacc[mt][r] + bv;
    }
}

// ---------------- MFMA attention: one (lead, head) per block; K/V staged once ----------------
template<int N>
__global__ __launch_bounds__(256) void k_attn_mfma(
    const bf16* __restrict__ qkv, bf16* __restrict__ out, int dmodel,
    int tokStride, int leadStride, int otokStride, int oleadStride, float scale) {
  constexpr int NT = N / 16;
  constexpr int NK = N / 32;
  constexpr int NIC = N / 64;
  __shared__ short Ks[N * 32];
  __shared__ short Vt[N * 32];
  __shared__ short Qs[2048];
  __shared__ short P[64 * N];

  const int lead = blockIdx.x;
  const int h = blockIdx.y;
  const short* base = (const short*)qkv + (size_t)lead * leadStride;
  const int qoff = h * 32, koff = dmodel + h * 32, voff = 2 * dmodel + h * 32;
  const int tid = threadIdx.x;
  const int l = tid & 63, w = tid >> 6;
  const int lr = l & 15, lk = l >> 4;

  for (int e = tid; e < N * 4; e += 256) {
    int j = e >> 2, kg = e & 3;
    short8 v = *(const short8*)(base + (size_t)j * tokStride + koff + kg * 8);
    *(short8*)(&Ks[(kg * N + j) * 8]) = v;
  }
  for (int e = tid; e < N * 32; e += 256) {
    int j = e >> 5, d = e & 31;
    Vt[((j >> 5) * 4 + ((j >> 3) & 3)) * 256 + d * 8 + (j & 7)] = base[(size_t)j * tokStride + voff + d];
  }
  __syncthreads();

  for (int ic = 0; ic < NIC; ic++) {
    {
      int r = tid >> 2, kg = tid & 3;
      short8 v = *(const short8*)(base + (size_t)(ic * 64 + r) * tokStride + qoff + kg * 8);
      *(short8*)(&Qs[(kg * 64 + r) * 8]) = v;
    }
    short8 aq = *(const short8*)(&Qs[(lk * 64 + w * 16 + lr) * 8]);
    floatx4 sa[NT];
    #pragma unroll
    for (int t = 0; t < NT; t++) {
      short8 bk = *(const short8*)(&Ks[(lk * N + t * 16 + lr) * 8]);
      floatx4 z = {0.f, 0.f, 0.f, 0.f};
      sa[t] = __builtin_amdgcn_mfma_f32_16x16x32_bf16(aq, bk, z, 0, 0, 0);
    }

    float mrow[4] = {-1e30f, -1e30f, -1e30f, -1e30f};
    #pragma unroll
    for (int t = 0; t < NT; t++)
      #pragma unroll
      for (int r = 0; r < 4; r++) {
        float s = fminf(fmaxf(sa[t][r] * scale, -50.f), 50.f);
        sa[t][r] = s;
        mrow[r] = fmaxf(mrow[r], s);
      }
    #pragma unroll
    for (int o = 1; o <= 8; o <<= 1)
      #pragma unroll
      for (int r = 0; r < 4; r++) mrow[r] = fmaxf(mrow[r], __shfl_xor(mrow[r], o));
    float srow[4] = {0.f, 0.f, 0.f, 0.f};
    #pragma unroll
    for (int t = 0; t < NT; t++)
      #pragma unroll
      for (int r = 0; r < 4; r++) {
        float p = __expf(sa[t][r] - mrow[r]);
        sa[t][r] = p;
        srow[r] += p;
      }
    #pragma unroll
    for (int o = 1; o <= 8; o <<= 1)
      #pragma unroll
      for (int r = 0; r < 4; r++) srow[r] += __shfl_xor(srow[r], o);
    float inv[4];
    #pragma unroll
    for (int r = 0; r < 4; r++) inv[r] = 1.f / srow[r];

    #pragma unroll
    for (int t = 0; t < NT; t++) {
      int c = t * 16 + lr;
      int kstep = c >> 5, kslot = (c >> 3) & 3, u = c & 7;
      #pragma unroll
      for (int r = 0; r < 4; r++) {
        int row = w * 16 + lk * 4 + r;
        P[((kstep * 4 + kslot) * 64 + row) * 8 + u] = f2bfs(sa[t][r] * inv[r]);
      }
    }

    floatx4 oacc[2] = {{0.f,0.f,0.f,0.f},{0.f,0.f,0.f,0.f}};
    #pragma unroll
    for (int ks = 0; ks < NK; ks++) {
      short8 ap = *(const short8*)(&P[((ks * 4 + lk) * 64 + w * 16 + lr) * 8]);
      #pragma unroll
      for (int ct = 0; ct < 2; ct++) {
        short8 bv = *(const short8*)(&Vt[((ks * 4 + lk) * 32 + ct * 16 + lr) * 8]);
        oacc[ct] = __builtin_amdgcn_mfma_f32_16x16x32_bf16(ap, bv, oacc[ct], 0, 0, 0);
      }
    }
    bf16* ob = out + (size_t)lead * oleadStride + h * 32;
    #pragma unroll
    for (int ct = 0; ct < 2; ct++)
      #pragma unroll
      for (int r = 0; r < 4; r++) {
        int tok = ic * 64 + w * 16 + lk * 4 + r;
        ob[(size_t)tok * otokStride + ct * 16 + lr] = __float2bfloat16(oacc[ct][r]);
      }
  }
}

extern "C" void kernel_launch(void* const* d_in, const int* in_sizes, int n_in,
                              void* d_out, int out_size, void* d_ws, size_t ws_size,
                              hipStream_t stream) {
  const float* msa_in    = (const float*)d_in[0];
  const float* pair_in   = (const float*)d_in[1];
  const float* row_ng    = (const float*)d_in[2];
  const float* row_nb    = (const float*)d_in[3];
  const float* row_qkv_w = (const float*)d_in[4];
  const float* row_qkv_b = (const float*)d_in[5];
  const float* row_out_w = (const float*)d_in[6];
  const float* row_out_b = (const float*)d_in[7];
  const float* col_ng    = (const float*)d_in[8];
  const float* col_nb    = (const float*)d_in[9];
  const float* col_qkv_w = (const float*)d_in[10];
  const float* col_qkv_b = (const float*)d_in[11];
  const float* col_out_w = (const float*)d_in[12];
  const float* col_out_b = (const float*)d_in[13];
  const float* ff_ng     = (const float*)d_in[14];
  const float* ff_nb     = (const float*)d_in[15];
  const float* ff_w1     = (const float*)d_in[16];
  const float* ff_b1     = (const float*)d_in[17];
  const float* ff_w2     = (const float*)d_in[18];
  const float* ff_b2     = (const float*)d_in[19];
  const float* op_ng     = (const float*)d_in[20];
  const float* op_nb     = (const float*)d_in[21];
  const float* op_a_w    = (const float*)d_in[22];
  const float* op_a_b    = (const float*)d_in[23];
  const float* op_b_w    = (const float*)d_in[24];
  const float* op_b_b    = (const float*)d_in[25];
  const float* op_out_w  = (const float*)d_in[26];
  const float* op_out_b  = (const float*)d_in[27];
  const float* tri_ng    = (const float*)d_in[28];
  const float* tri_nb    = (const float*)d_in[29];
  const float* tri_qkv_w = (const float*)d_in[30];
  const float* tri_qkv_b = (const float*)d_in[31];
  const float* tri_out_w = (const float*)d_in[32];
  const float* tri_out_b = (const float*)d_in[33];

  const int MT = S_ * L_;   // 16384
  const int PT = L_ * L_;   // 65536

  // ---- arena (byte offsets) ----
  char* ws = (char*)d_ws;
  float* msa_f  = (float*)(ws);                    // 16 MB
  float* pair_f = (float*)(ws + 16777216);         // 32 MB
  char*  X      = ws + 50331648;                   // 48 MB scratch (qkv bf16 / ffh bf16)
  bf16*  ln_b   = (bf16*)(ws + 100663296);         // 16 MB
  bf16*  ao_b   = (bf16*)(ws + 117440512);         // 16 MB
  bf16*  a_t    = (bf16*)(ws + 136314880);         // 1 MB
  bf16*  b_t    = (bf16*)(ws + 137363456);         // 1 MB
  bf16*  wts    = (bf16*)(ws + 138412032);         // ~2.6 MB
  float* bias_ab = (float*)(ws + 141557760);       // 64 floats

  bf16* row_qkv_wt = wts;                 // 768*256
  bf16* col_qkv_wt = row_qkv_wt + 196608;
  bf16* row_out_wt = col_qkv_wt + 196608; // 256*256
  bf16* col_out_wt = row_out_wt + 65536;
  bf16* ff_w1t     = col_out_wt + 65536;  // 1024*256
  bf16* ff_w2t     = ff_w1t + 262144;     // 256*1024
  bf16* op_ab_wt   = ff_w2t + 262144;     // 64*256
  bf16* op_out_wt  = op_ab_wt + 16384;    // 128*1024 (ec-permuted)
  bf16* tri_qkv_wt = op_out_wt + 131072;  // 384*128
  bf16* tri_out_wt = tri_qkv_wt + 49152;  // 128*128

  bf16* qkv_bf = (bf16*)X;
  bf16* ffh    = (bf16*)X;

  float* dout_msa  = (float*)d_out;
  float* dout_pair = (float*)d_out + (size_t)MT * DM_;

  const float scale = 0.17677669529663687f; // 1/sqrt(32)

  // ---- weight prep: ONE launch (1104 transpose blocks + 512 permute blocks) ----
  WtJobs jobs;
  jobs.j[0] = {row_qkv_w, row_qkv_wt, 256, 768, 192};
  jobs.j[1] = {col_qkv_w, col_qkv_wt, 256, 768, 192};
  jobs.j[2] = {row_out_w, row_out_wt, 256, 256, 64};
  jobs.j[3] = {col_out_w, col_out_wt, 256, 256, 64};
  jobs.j[4] = {ff_w1, ff_w1t, 256, 1024, 256};
  jobs.j[5] = {ff_w2, ff_w2t, 1024, 256, 256};
  jobs.j[6] = {op_a_w, op_ab_wt, 256, 32, 8};
  jobs.j[7] = {op_b_w, op_ab_wt + 32 * 256, 256, 32, 8};
  jobs.j[8] = {tri_qkv_w, tri_qkv_wt, 128, 384, 48};
  jobs.j[9] = {tri_out_w, tri_out_wt, 128, 128, 16};
  jobs.opW = op_out_w; jobs.opWt = op_out_wt;
  jobs.ba = op_a_b; jobs.bb = op_b_b; jobs.bias_ab = bias_ab;
  k_wt_all<<<1616, 256, 0, stream>>>(jobs);

  // ---- 1. row attention (attend over L) ----
  k_ln<<<MT / 4, 256, 0, stream>>>(msa_in, ln_b, row_ng, row_nb, DM_);
  k_gemm64<2,0><<<dim3(12, 256), 256, 0, stream>>>(ln_b, row_qkv_wt, row_qkv_b, nullptr, qkv_bf, nullptr, nullptr, MT, 768, 256, 1.f);
  k_attn_mfma<256><<<dim3(S_, H_), 256, 0, stream>>>(qkv_bf, ao_b, DM_, 768, L_ * 768, DM_, L_ * DM_, scale);
  k_gemm64<4,0><<<dim3(4, 256), 256, 0, stream>>>(ao_b, row_out_wt, row_out_b, msa_f, nullptr, msa_in, nullptr, MT, DM_, DM_, 1.f);

  // ---- 2. column attention (attend over S) ----
  k_ln<<<MT / 4, 256, 0, stream>>>(msa_f, ln_b, col_ng, col_nb, DM_);
  k_gemm64<2,0><<<dim3(12, 256), 256, 0, stream>>>(ln_b, col_qkv_wt, col_qkv_b, nullptr, qkv_bf, nullptr, nullptr, MT, 768, 256, 1.f);
  k_attn_mfma<64><<<dim3(L_, H_), 256, 0, stream>>>(qkv_bf, ao_b, DM_, L_ * 768, 768, L_ * DM_, DM_, scale);
  k_gemm64<1,0><<<dim3(4, 256), 256, 0, stream>>>(ao_b, col_out_wt, col_out_b, msa_f, nullptr, nullptr, nullptr, MT, DM_, DM_, 1.f);

  // ---- 3. feed-forward (down-proj also writes d_out msa) ----
  k_ln<<<MT / 4, 256, 0, stream>>>(msa_f, ln_b, ff_ng, ff_nb, DM_);
  k_gemm64<3,0><<<dim3(16, 256), 256, 0, stream>>>(ln_b, ff_w1t, ff_b1, nullptr, ffh, nullptr, nullptr, MT, 1024, 256, 1.f);
  k_gemm64<5,0><<<dim3(4, 256), 256, 0, stream>>>(ffh, ff_w2t, ff_b2, msa_f, nullptr, nullptr, dout_msa, MT, DM_, 1024, 1.f);

  // ---- 4. outer product mean -> pair (LN fused; transposed write; grid.x==1) ----
  k_gemm64<6,1><<<dim3(1, 256), 256, 0, stream>>>(nullptr, op_ab_wt, bias_ab, nullptr, a_t, nullptr, (float*)b_t, MT, 64, 256, 1.f, msa_f, op_ng, op_nb);
  k_opm_fused<<<dim3(8, L_), 512, 0, stream>>>(a_t, b_t, op_out_wt, op_out_b, pair_in, pair_f);

  // ---- 5. triangle attention (out-proj writes d_out pair directly) ----
  k_ln<<<PT / 4, 256, 0, stream>>>(pair_f, ln_b, tri_ng, tri_nb, DP_);
  k_gemm64<2,0><<<dim3(6, 1024), 256, 0, stream>>>(ln_b, tri_qkv_wt, tri_qkv_b, nullptr, qkv_bf, nullptr, nullptr, PT, 384, DP_, 1.f);
  k_attn_mfma<256><<<dim3(L_, HT_), 256, 0, stream>>>(qkv_bf, ao_b, DP_, 384, L_ * 384, DP_, L_ * DP_, scale);
  k_gemm64<4,0><<<dim3(2, 1024), 256, 0, stream>>>(ao_b, tri_out_wt, tri_out_b, dout_pair, nullptr, pair_f, nullptr, PT, DP_, DP_, 1.f);
}